// Round 6
// baseline (1538.239 us; speedup 1.0000x reference)
//
#include <hip/hip_runtime.h>
#include <hip/hip_fp16.h>
#include <hip/hip_bf16.h>

typedef __attribute__((ext_vector_type(8))) short bf16x8;
typedef __attribute__((ext_vector_type(4))) float f32x4;

constexpr int EMBED = 64;
constexpr int RBF   = 16;
constexpr int NPB   = 32;     // nodes per block in edge_agg kernel
constexpr int SCAN_TILE = 1024;

__device__ __forceinline__ short f2bf(float f) {
    __hip_bfloat16 h = __float2bfloat16(f);   // RNE
    return *reinterpret_cast<short*>(&h);
}
__device__ __forceinline__ unsigned pk_bf(float lo, float hi) {
    unsigned l = (unsigned short)f2bf(lo);
    unsigned h = (unsigned short)f2bf(hi);
    return l | (h << 16);
}
__device__ __forceinline__ float silu(float x) {
    return x * __builtin_amdgcn_rcpf(1.0f + __expf(-x));
}
// channel map: lane c, acc t -> channel (t&1) + 2c + 32*(t>>1)
__device__ __forceinline__ int gmap(int t, int c) {
    return (t & 1) + 2 * c + 32 * (t >> 1);
}

// ======================= CSR construction ==================================
__global__ __launch_bounds__(256) void k_hist(
    const int* __restrict__ ei, int* __restrict__ counts, long long E)
{
    long long i = (long long)blockIdx.x * 256 + threadIdx.x;
    if (i < E) atomicAdd(&counts[ei[i]], 1);
}

__global__ __launch_bounds__(256) void k_scan1(
    const int* __restrict__ counts, int* __restrict__ offsets,
    int* __restrict__ bsums, int nn)
{
    __shared__ int lds[256];
    const int t = threadIdx.x;
    const int base = blockIdx.x * SCAN_TILE;
    int v[4]; int s = 0;
#pragma unroll
    for (int j = 0; j < 4; ++j) {
        const int i = base + t * 4 + j;
        v[j] = (i < nn) ? counts[i] : 0;
        s += v[j];
    }
    lds[t] = s;
    __syncthreads();
    for (int off = 1; off < 256; off <<= 1) {
        int x = (t >= off) ? lds[t - off] : 0;
        __syncthreads();
        lds[t] += x;
        __syncthreads();
    }
    int run = lds[t] - s;   // exclusive prefix of this thread's chunk
    if (t == 255) bsums[blockIdx.x] = lds[255];
#pragma unroll
    for (int j = 0; j < 4; ++j) {
        const int i = base + t * 4 + j;
        if (i < nn) offsets[i] = run;
        run += v[j];
    }
}

__global__ void k_scan2(int* __restrict__ bsums, int nblk)
{
    if (threadIdx.x == 0 && blockIdx.x == 0) {
        int a = 0;
        for (int i = 0; i < nblk; ++i) { int t = bsums[i]; bsums[i] = a; a += t; }
    }
}

__global__ __launch_bounds__(256) void k_scan3(
    int* __restrict__ offsets, const int* __restrict__ bsums,
    int* __restrict__ counts, int nn, int Etot)
{
    const int base = blockIdx.x * SCAN_TILE;
    const int add = bsums[blockIdx.x];
#pragma unroll
    for (int j = 0; j < 4; ++j) {
        const int i = base + threadIdx.x * 4 + j;
        if (i < nn) { offsets[i] += add; counts[i] = 0; }
    }
    if (blockIdx.x == 0 && threadIdx.x == 0) offsets[nn] = Etot;
}

__global__ __launch_bounds__(256) void k_scatter(
    const int* __restrict__ ei, const int* __restrict__ offsets,
    int* __restrict__ cursor, int* __restrict__ eid, long long E)
{
    long long i = (long long)blockIdx.x * 256 + threadIdx.x;
    if (i < E) {
        const int r = ei[i];
        const int p = atomicAdd(&cursor[r], 1);
        eid[offsets[r] + p] = (int)i;
    }
}

// ======================= edge + LDS-aggregate kernel =======================
// Block owns nodes [n0, n0+NPB); walks its CSR edge span in 16-edge MFMA
// tiles; scatter-adds messages into bank-padded LDS accumulator; writes each
// agg row to global exactly once. Zero global atomics.
__global__ __launch_bounds__(256, 2) void edge_agg_kernel(
    const float* __restrict__ coord,
    const float* __restrict__ rbf,
    const int* __restrict__ ei,
    const float* __restrict__ W1,
    const float* __restrict__ b1,
    const float* __restrict__ W2,
    const float* __restrict__ b2,
    const int* __restrict__ offsets,
    const int* __restrict__ eid,
    float* __restrict__ agg,
    int nn, long long E)
{
    __shared__ float aggl[NPB][EMBED + 1];              // +1 pad: bank spread
    __shared__ __align__(16) short lds_s[4][16 * 64];   // per-wave msg tile

    const int tid  = threadIdx.x;
    const int lane = tid & 63;
    const int wave = tid >> 6;
    const int g = lane >> 4;
    const int c = lane & 15;
    const int n0 = blockIdx.x * NPB;
    const int n1 = min(n0 + NPB, nn);

    for (int i = tid; i < NPB * (EMBED + 1); i += 256)
        (&aggl[0][0])[i] = 0.0f;

    const int ebeg = offsets[n0];
    const int eend = offsets[n1];

    // ---- B fragments with gamma channel map ----
    int ch[4];
#pragma unroll
    for (int t = 0; t < 4; ++t) ch[t] = gmap(t, c);

    bf16x8 b1f[4];
#pragma unroll
    for (int t = 0; t < 4; ++t)
#pragma unroll
        for (int j = 0; j < 8; ++j) {
            const int k = g * 8 + j;
            b1f[t][j] = (k <= RBF) ? f2bf(W1[k * EMBED + ch[t]]) : (short)0;
        }
    bf16x8 b2f[2][4];
#pragma unroll
    for (int kk = 0; kk < 2; ++kk)
#pragma unroll
        for (int t = 0; t < 4; ++t)
#pragma unroll
            for (int j = 0; j < 8; ++j) {
                const int k = kk * 32 + g * 8 + j;
                b2f[kk][t][j] = f2bf(W2[k * EMBED + ch[t]]);
            }
    float b1v[4], b2v[4];
#pragma unroll
    for (int t = 0; t < 4; ++t) { b1v[t] = b1[ch[t]]; b2v[t] = b2[ch[t]]; }

    __syncthreads();

    char* const sl = reinterpret_cast<char*>(lds_s[wave]);

    for (int tb = ebeg + wave * 16; tb < eend; tb += 64) {
        const int nval = min(16, eend - tb);
        const bool lv = (c < nval);
        int e = 0, rowg = n0;
        if (lv) { e = eid[tb + c]; rowg = ei[e]; }
        const int lrow_c = rowg - n0;

        // ---- A1 fragment: m=c (edge), k=g*8+j ----
        bf16x8 a = {};
        if (g < 2) {
            if (lv) {
                const float4 p0 = *reinterpret_cast<const float4*>(rbf + (long long)e * RBF + g * 8);
                const float4 p1 = *reinterpret_cast<const float4*>(rbf + (long long)e * RBF + g * 8 + 4);
                a[0] = f2bf(p0.x); a[1] = f2bf(p0.y); a[2] = f2bf(p0.z); a[3] = f2bf(p0.w);
                a[4] = f2bf(p1.x); a[5] = f2bf(p1.y); a[6] = f2bf(p1.z); a[7] = f2bf(p1.w);
            }
        } else if (g == 2) {
            if (lv) {   // angle, faithful to reference
                const int col = ei[E + e];
                const float vx = coord[rowg * 3 + 0] - coord[col * 3 + 0];
                const float vy = coord[rowg * 3 + 1] - coord[col * 3 + 1];
                const float vz = coord[rowg * 3 + 2] - coord[col * 3 + 2];
                const float sq = vx * vx + vy * vy + vz * vz;
                const float nrm = fmaxf(sqrtf(sq), 1e-12f);
                const float inv = 1.0f / nrm;
                const float ux = vx * inv, uy = vy * inv, uz = vz * inv;
                const float s2 = ux * ux + uy * uy + uz * uz;
                const float cosang = fminf(fmaxf(-s2, -1.0f), 1.0f);
                a[0] = f2bf(acosf(cosang));
            }
        }

        // ---- GEMM1 ----
        f32x4 acc1[4];
#pragma unroll
        for (int t = 0; t < 4; ++t) {
            f32x4 ci = {b1v[t], b1v[t], b1v[t], b1v[t]};
            acc1[t] = __builtin_amdgcn_mfma_f32_16x16x32_bf16(a, b1f[t], ci, 0, 0, 0);
        }

        // ---- SiLU + packed bf16x2 swizzled LDS write (identity channel pos) ----
#pragma unroll
        for (int r = 0; r < 4; ++r) {
            const int erow = g * 4 + r;
            const int swz = (erow & 7) << 4;
            const float s0 = silu(acc1[0][r]);
            const float s1 = silu(acc1[1][r]);
            const float s2v = silu(acc1[2][r]);
            const float s3 = silu(acc1[3][r]);
            *reinterpret_cast<unsigned*>(sl + erow * 128 + ((4 * c) ^ swz))      = pk_bf(s0, s1);
            *reinterpret_cast<unsigned*>(sl + erow * 128 + ((64 + 4 * c) ^ swz)) = pk_bf(s2v, s3);
        }
        __builtin_amdgcn_wave_barrier();

        // ---- A2: m=c, k natural (channels stored at own positions) ----
        bf16x8 a2[2];
#pragma unroll
        for (int kk = 0; kk < 2; ++kk) {
            const int byte = c * 128 + ((kk * 64 + g * 16) ^ ((c & 7) << 4));
            a2[kk] = *reinterpret_cast<const bf16x8*>(sl + byte);
        }

        // ---- GEMM2 ----
        f32x4 acc2[4];
#pragma unroll
        for (int t = 0; t < 4; ++t) {
            f32x4 ci = {b2v[t], b2v[t], b2v[t], b2v[t]};
            acc2[t] = __builtin_amdgcn_mfma_f32_16x16x32_bf16(a2[0], b2f[0][t], ci, 0, 0, 0);
            acc2[t] = __builtin_amdgcn_mfma_f32_16x16x32_bf16(a2[1], b2f[1][t], acc2[t], 0, 0, 0);
        }

        // ---- LDS scatter (block-local, bank-padded) ----
#pragma unroll
        for (int r = 0; r < 4; ++r) {
            const int lr = __shfl(lrow_c, g * 4 + r, 64);
            if (g * 4 + r < nval) {
#pragma unroll
                for (int t = 0; t < 4; ++t)
                    atomicAdd(&aggl[lr][ch[t]], acc2[t][r]);
            }
        }
        __builtin_amdgcn_wave_barrier();
    }

    __syncthreads();
    for (int i = tid; i < NPB * EMBED; i += 256) {
        const int rr = i >> 6, cc = i & 63;
        if (n0 + rr < nn)
            agg[(long long)(n0 + rr) * EMBED + cc] = aggl[rr][cc];
    }
}

// ======================= fallback: fp32 atomic edge kernel =================
__global__ __launch_bounds__(256, 2) void edge_kernel_atomic(
    const float* __restrict__ coord, const float* __restrict__ rbf,
    const int* __restrict__ edge_index, const float* __restrict__ W1,
    const float* __restrict__ b1, const float* __restrict__ W2,
    const float* __restrict__ b2, float* __restrict__ agg, long long E)
{
    __shared__ int lds_row[256];
    __shared__ __align__(16) short lds_s[4][16 * 64];
    const int tid = threadIdx.x, lane = tid & 63, wave = tid >> 6;
    const int g = lane >> 4, c = lane & 15;
    const long long blk_e0 = (long long)blockIdx.x * 256;
    {
        long long e = blk_e0 + tid;
        lds_row[tid] = (e < E) ? edge_index[e] : 0;
    }
    __builtin_amdgcn_wave_barrier();
    int ch[4];
#pragma unroll
    for (int t = 0; t < 4; ++t) ch[t] = gmap(t, c);
    bf16x8 b1f[4];
#pragma unroll
    for (int t = 0; t < 4; ++t)
#pragma unroll
        for (int j = 0; j < 8; ++j) {
            const int k = g * 8 + j;
            b1f[t][j] = (k <= RBF) ? f2bf(W1[k * EMBED + ch[t]]) : (short)0;
        }
    bf16x8 b2f[2][4];
#pragma unroll
    for (int kk = 0; kk < 2; ++kk)
#pragma unroll
        for (int t = 0; t < 4; ++t)
#pragma unroll
            for (int j = 0; j < 8; ++j)
                b2f[kk][t][j] = f2bf(W2[(kk * 32 + g * 8 + j) * EMBED + ch[t]]);
    float b1v[4], b2v[4];
#pragma unroll
    for (int t = 0; t < 4; ++t) { b1v[t] = b1[ch[t]]; b2v[t] = b2[ch[t]]; }

    char* const sl = reinterpret_cast<char*>(lds_s[wave]);
    const long long wave_e0 = blk_e0 + (long long)wave * 64;
#pragma unroll 1
    for (int mt = 0; mt < 4; ++mt) {
        const long long e0 = wave_e0 + mt * 16;
        if (e0 >= E) break;
        const int eloc0 = wave * 64 + mt * 16;
        bf16x8 a = {};
        const long long ea = e0 + c;
        const bool ev = (ea < E);
        if (g < 2) {
            if (ev) {
                const float4 p0 = *reinterpret_cast<const float4*>(rbf + ea * RBF + g * 8);
                const float4 p1 = *reinterpret_cast<const float4*>(rbf + ea * RBF + g * 8 + 4);
                a[0] = f2bf(p0.x); a[1] = f2bf(p0.y); a[2] = f2bf(p0.z); a[3] = f2bf(p0.w);
                a[4] = f2bf(p1.x); a[5] = f2bf(p1.y); a[6] = f2bf(p1.z); a[7] = f2bf(p1.w);
            }
        } else if (g == 2 && ev) {
            const int row = lds_row[eloc0 + c];
            const int col = edge_index[E + ea];
            const float vx = coord[row * 3 + 0] - coord[col * 3 + 0];
            const float vy = coord[row * 3 + 1] - coord[col * 3 + 1];
            const float vz = coord[row * 3 + 2] - coord[col * 3 + 2];
            const float nrm = fmaxf(sqrtf(vx * vx + vy * vy + vz * vz), 1e-12f);
            const float inv = 1.0f / nrm;
            const float ux = vx * inv, uy = vy * inv, uz = vz * inv;
            const float cosang = fminf(fmaxf(-(ux * ux + uy * uy + uz * uz), -1.0f), 1.0f);
            a[0] = f2bf(acosf(cosang));
        }
        f32x4 acc1[4];
#pragma unroll
        for (int t = 0; t < 4; ++t) {
            f32x4 ci = {b1v[t], b1v[t], b1v[t], b1v[t]};
            acc1[t] = __builtin_amdgcn_mfma_f32_16x16x32_bf16(a, b1f[t], ci, 0, 0, 0);
        }
#pragma unroll
        for (int r = 0; r < 4; ++r) {
            const int erow = g * 4 + r;
            const int swz = (erow & 7) << 4;
            *reinterpret_cast<unsigned*>(sl + erow * 128 + ((4 * c) ^ swz)) =
                pk_bf(silu(acc1[0][r]), silu(acc1[1][r]));
            *reinterpret_cast<unsigned*>(sl + erow * 128 + ((64 + 4 * c) ^ swz)) =
                pk_bf(silu(acc1[2][r]), silu(acc1[3][r]));
        }
        __builtin_amdgcn_wave_barrier();
        bf16x8 a2[2];
#pragma unroll
        for (int kk = 0; kk < 2; ++kk)
            a2[kk] = *reinterpret_cast<const bf16x8*>(sl + c * 128 + ((kk * 64 + g * 16) ^ ((c & 7) << 4)));
        f32x4 acc2[4];
#pragma unroll
        for (int t = 0; t < 4; ++t) {
            f32x4 ci = {b2v[t], b2v[t], b2v[t], b2v[t]};
            acc2[t] = __builtin_amdgcn_mfma_f32_16x16x32_bf16(a2[0], b2f[0][t], ci, 0, 0, 0);
            acc2[t] = __builtin_amdgcn_mfma_f32_16x16x32_bf16(a2[1], b2f[1][t], acc2[t], 0, 0, 0);
        }
#pragma unroll
        for (int r = 0; r < 4; ++r) {
            const long long eat = e0 + g * 4 + r;
            if (eat < E) {
                float* const dst = agg + (long long)lds_row[eloc0 + g * 4 + r] * EMBED;
#pragma unroll
                for (int t = 0; t < 4; ++t)
                    atomicAdd(dst + ch[t], acc2[t][r]);
            }
        }
        __builtin_amdgcn_wave_barrier();
    }
}

// ======================= node kernel (fp32 agg, in-place safe) =============
__global__ __launch_bounds__(256) void node_kernel(
    const float* __restrict__ x, const float* __restrict__ aggv,
    const float* __restrict__ W3, const float* __restrict__ b3,
    const float* __restrict__ W4, const float* __restrict__ b4,
    float* __restrict__ out, int nn)
{
    __shared__ __align__(16) float lds_s[4][EMBED];
    const int lane = threadIdx.x & 63;
    const int wave = threadIdx.x >> 6;

    float w3c[EMBED], w4c[EMBED];
#pragma unroll
    for (int j = 0; j < EMBED; ++j) w3c[j] = W3[j * EMBED + lane];
#pragma unroll
    for (int j = 0; j < EMBED; ++j) w4c[j] = W4[j * EMBED + lane];
    const float b3v = b3[lane];
    const float b4v = b4[lane];

    const float4* s4 = reinterpret_cast<const float4*>(lds_s[wave]);
    const int wid = blockIdx.x * 4 + wave;
    const int nw  = gridDim.x * 4;
    for (int n = wid; n < nn; n += nw) {
        const long long base = (long long)n * EMBED + lane;
        const float aval = aggv[base];

        lds_s[wave][lane] = aval;
        __builtin_amdgcn_wave_barrier();
        float acc = b3v;
#pragma unroll
        for (int j4 = 0; j4 < EMBED / 4; ++j4) {
            const float4 sv = s4[j4];
            acc = fmaf(sv.x, w3c[4 * j4 + 0], acc);
            acc = fmaf(sv.y, w3c[4 * j4 + 1], acc);
            acc = fmaf(sv.z, w3c[4 * j4 + 2], acc);
            acc = fmaf(sv.w, w3c[4 * j4 + 3], acc);
        }
        const float s = acc * __builtin_amdgcn_rcpf(1.0f + __expf(-acc));
        __builtin_amdgcn_wave_barrier();
        lds_s[wave][lane] = s;
        __builtin_amdgcn_wave_barrier();
        float acc2 = b4v;
#pragma unroll
        for (int j4 = 0; j4 < EMBED / 4; ++j4) {
            const float4 sv = s4[j4];
            acc2 = fmaf(sv.x, w4c[4 * j4 + 0], acc2);
            acc2 = fmaf(sv.y, w4c[4 * j4 + 1], acc2);
            acc2 = fmaf(sv.z, w4c[4 * j4 + 2], acc2);
            acc2 = fmaf(sv.w, w4c[4 * j4 + 3], acc2);
        }
        __builtin_amdgcn_wave_barrier();
        out[base] = x[base] + acc2;
    }
}

// ===========================================================================
extern "C" void kernel_launch(void* const* d_in, const int* in_sizes, int n_in,
                              void* d_out, int out_size, void* d_ws, size_t ws_size,
                              hipStream_t stream) {
    const float* x      = (const float*)d_in[0];
    const float* coord  = (const float*)d_in[1];
    const float* rbf    = (const float*)d_in[2];
    const int*   ei     = (const int*)d_in[3];
    const float* W1 = (const float*)d_in[4];
    const float* b1 = (const float*)d_in[5];
    const float* W2 = (const float*)d_in[6];
    const float* b2 = (const float*)d_in[7];
    const float* W3 = (const float*)d_in[8];
    const float* b3 = (const float*)d_in[9];
    const float* W4 = (const float*)d_in[10];
    const float* b4 = (const float*)d_in[11];
    float* out = (float*)d_out;

    const long long E = in_sizes[3] / 2;
    const int nn = in_sizes[0] / EMBED;
    const int nscan = (nn + SCAN_TILE - 1) / SCAN_TILE;
    const int nsPad = (nscan + 63) & ~63;

    int* counts  = (int*)d_ws;
    int* offsets = counts + nn;
    int* bsums   = offsets + nn + 1;
    int* eid     = bsums + nsPad;
    const size_t needed = sizeof(int) * ((size_t)nn + (nn + 1) + nsPad + E);

    const unsigned egrid = (unsigned)((E + 255) / 256);

    if (ws_size >= needed) {
        // ---- CSR build ----
        hipMemsetAsync(counts, 0, sizeof(int) * nn, stream);
        k_hist<<<dim3(egrid), dim3(256), 0, stream>>>(ei, counts, E);
        k_scan1<<<dim3((unsigned)nscan), dim3(256), 0, stream>>>(counts, offsets, bsums, nn);
        k_scan2<<<dim3(1), dim3(64), 0, stream>>>(bsums, nscan);
        k_scan3<<<dim3((unsigned)nscan), dim3(256), 0, stream>>>(offsets, bsums, counts, nn, (int)E);
        k_scatter<<<dim3(egrid), dim3(256), 0, stream>>>(ei, offsets, counts, eid, E);
        // ---- edge + LDS aggregation (atomic-free), agg -> d_out ----
        const unsigned ngrid = (unsigned)((nn + NPB - 1) / NPB);
        edge_agg_kernel<<<dim3(ngrid), dim3(256), 0, stream>>>(
            coord, rbf, ei, W1, b1, W2, b2, offsets, eid, out, nn, E);
    } else {
        // ---- fallback: fp32 global atomics into d_out ----
        hipMemsetAsync(out, 0, (size_t)nn * EMBED * sizeof(float), stream);
        edge_kernel_atomic<<<dim3((unsigned)((E + 255) / 256)), dim3(256), 0, stream>>>(
            coord, rbf, ei, W1, b1, W2, b2, out, E);
    }
    // ---- node MLP, in place over d_out ----
    node_kernel<<<dim3(2048), dim3(256), 0, stream>>>(
        x, out, W3, b3, W4, b4, out, nn);
}

// Round 7
// 1015.780 us; speedup vs baseline: 1.5143x; 1.5143x over previous
//
#include <hip/hip_runtime.h>
#include <hip/hip_fp16.h>
#include <hip/hip_bf16.h>

typedef __attribute__((ext_vector_type(8))) short bf16x8;
typedef __attribute__((ext_vector_type(4))) float f32x4;

constexpr int EMBED = 64;
constexpr int RBF   = 16;
constexpr int SCAN_TILE = 1024;

__device__ __forceinline__ short f2bf(float f) {
    __hip_bfloat16 h = __float2bfloat16(f);   // RNE
    return *reinterpret_cast<short*>(&h);
}
__device__ __forceinline__ unsigned pk_bf(float lo, float hi) {
    unsigned l = (unsigned short)f2bf(lo);
    unsigned h = (unsigned short)f2bf(hi);
    return l | (h << 16);
}
__device__ __forceinline__ float bf2f(unsigned bits16) {
    return __uint_as_float(bits16 << 16);
}
__device__ __forceinline__ float silu(float x) {
    return x * __builtin_amdgcn_rcpf(1.0f + __expf(-x));
}

// ======================= CSR construction (proven round 6) =================
__global__ __launch_bounds__(256) void k_hist(
    const int* __restrict__ ei, int* __restrict__ counts, long long E)
{
    long long i = (long long)blockIdx.x * 256 + threadIdx.x;
    if (i < E) atomicAdd(&counts[ei[i]], 1);
}

__global__ __launch_bounds__(256) void k_scan1(
    const int* __restrict__ counts, int* __restrict__ offsets,
    int* __restrict__ bsums, int nn)
{
    __shared__ int lds[256];
    const int t = threadIdx.x;
    const int base = blockIdx.x * SCAN_TILE;
    int v[4]; int s = 0;
#pragma unroll
    for (int j = 0; j < 4; ++j) {
        const int i = base + t * 4 + j;
        v[j] = (i < nn) ? counts[i] : 0;
        s += v[j];
    }
    lds[t] = s;
    __syncthreads();
    for (int off = 1; off < 256; off <<= 1) {
        int x = (t >= off) ? lds[t - off] : 0;
        __syncthreads();
        lds[t] += x;
        __syncthreads();
    }
    int run = lds[t] - s;
    if (t == 255) bsums[blockIdx.x] = lds[255];
#pragma unroll
    for (int j = 0; j < 4; ++j) {
        const int i = base + t * 4 + j;
        if (i < nn) offsets[i] = run;
        run += v[j];
    }
}

__global__ void k_scan2(int* __restrict__ bsums, int nblk)
{
    if (threadIdx.x == 0 && blockIdx.x == 0) {
        int a = 0;
        for (int i = 0; i < nblk; ++i) { int t = bsums[i]; bsums[i] = a; a += t; }
    }
}

__global__ __launch_bounds__(256) void k_scan3(
    int* __restrict__ offsets, const int* __restrict__ bsums,
    int* __restrict__ counts, int nn, int Etot)
{
    const int base = blockIdx.x * SCAN_TILE;
    const int add = bsums[blockIdx.x];
#pragma unroll
    for (int j = 0; j < 4; ++j) {
        const int i = base + threadIdx.x * 4 + j;
        if (i < nn) { offsets[i] += add; counts[i] = 0; }
    }
    if (blockIdx.x == 0 && threadIdx.x == 0) offsets[nn] = Etot;
}

__global__ __launch_bounds__(256) void k_scatter(
    const int* __restrict__ ei, const int* __restrict__ offsets,
    int* __restrict__ cursor, int* __restrict__ eid, long long E)
{
    long long i = (long long)blockIdx.x * 256 + threadIdx.x;
    if (i < E) {
        const int r = ei[i];
        const int p = atomicAdd(&cursor[r], 1);
        eid[offsets[r] + p] = (int)i;
    }
}

// ======================= phase 1: edge MLP -> msg (natural order) ==========
// Channel map gamma(t,c)=4c+t: lane c holds channels 4c..4c+3 -> one 8-byte
// contiguous chunk of the 128-B bf16 message row. Coalesced rbf reads,
// coalesced msg stores, zero atomics.
__global__ __launch_bounds__(256) void edge_msg_kernel(
    const float* __restrict__ coord,
    const float* __restrict__ rbf,
    const int* __restrict__ ei,
    const float* __restrict__ W1,
    const float* __restrict__ b1,
    const float* __restrict__ W2,
    const float* __restrict__ b2,
    unsigned* __restrict__ msg,   // E x 32 dwords (64 bf16 per edge)
    long long E)
{
    __shared__ __align__(16) short lds_s[4][16 * 64];

    const int tid  = threadIdx.x;
    const int lane = tid & 63;
    const int wave = tid >> 6;
    const int g = lane >> 4;
    const int c = lane & 15;
    const long long blk_e0 = (long long)blockIdx.x * 256;

    // ---- B fragments, channel map 4c+t ----
    int ch[4];
#pragma unroll
    for (int t = 0; t < 4; ++t) ch[t] = 4 * c + t;

    bf16x8 b1f[4];
#pragma unroll
    for (int t = 0; t < 4; ++t)
#pragma unroll
        for (int j = 0; j < 8; ++j) {
            const int k = g * 8 + j;
            b1f[t][j] = (k <= RBF) ? f2bf(W1[k * EMBED + ch[t]]) : (short)0;
        }
    bf16x8 b2f[2][4];
#pragma unroll
    for (int kk = 0; kk < 2; ++kk)
#pragma unroll
        for (int t = 0; t < 4; ++t)
#pragma unroll
            for (int j = 0; j < 8; ++j)
                b2f[kk][t][j] = f2bf(W2[(kk * 32 + g * 8 + j) * EMBED + ch[t]]);
    float b1v[4], b2v[4];
#pragma unroll
    for (int t = 0; t < 4; ++t) { b1v[t] = b1[ch[t]]; b2v[t] = b2[ch[t]]; }

    char* const sl = reinterpret_cast<char*>(lds_s[wave]);
    const long long wave_e0 = blk_e0 + (long long)wave * 64;

#pragma unroll 1
    for (int mt = 0; mt < 4; ++mt) {
        const long long e0 = wave_e0 + mt * 16;
        if (e0 >= E) break;

        // ---- A1: m=c (edge), k=g*8+j ----
        bf16x8 a = {};
        const long long ea = e0 + c;
        const bool ev = (ea < E);
        if (g < 2) {
            if (ev) {
                const float4 p0 = *reinterpret_cast<const float4*>(rbf + ea * RBF + g * 8);
                const float4 p1 = *reinterpret_cast<const float4*>(rbf + ea * RBF + g * 8 + 4);
                a[0] = f2bf(p0.x); a[1] = f2bf(p0.y); a[2] = f2bf(p0.z); a[3] = f2bf(p0.w);
                a[4] = f2bf(p1.x); a[5] = f2bf(p1.y); a[6] = f2bf(p1.z); a[7] = f2bf(p1.w);
            }
        } else if (g == 2 && ev) {
            // angle, faithful to reference
            const int row = ei[ea];
            const int col = ei[E + ea];
            const float vx = coord[row * 3 + 0] - coord[col * 3 + 0];
            const float vy = coord[row * 3 + 1] - coord[col * 3 + 1];
            const float vz = coord[row * 3 + 2] - coord[col * 3 + 2];
            const float nrm = fmaxf(sqrtf(vx * vx + vy * vy + vz * vz), 1e-12f);
            const float inv = 1.0f / nrm;
            const float ux = vx * inv, uy = vy * inv, uz = vz * inv;
            const float cosang = fminf(fmaxf(-(ux * ux + uy * uy + uz * uz), -1.0f), 1.0f);
            a[0] = f2bf(acosf(cosang));
        }

        // ---- GEMM1 + bias ----
        f32x4 acc1[4];
#pragma unroll
        for (int t = 0; t < 4; ++t) {
            f32x4 ci = {b1v[t], b1v[t], b1v[t], b1v[t]};
            acc1[t] = __builtin_amdgcn_mfma_f32_16x16x32_bf16(a, b1f[t], ci, 0, 0, 0);
        }

        // ---- SiLU + packed bf16 swizzled LDS write (one b64 per r) ----
#pragma unroll
        for (int r = 0; r < 4; ++r) {
            const int erow = g * 4 + r;
            const int swz = (erow & 7) << 4;
            uint2 w;
            w.x = pk_bf(silu(acc1[0][r]), silu(acc1[1][r]));
            w.y = pk_bf(silu(acc1[2][r]), silu(acc1[3][r]));
            *reinterpret_cast<uint2*>(sl + erow * 128 + ((8 * c) ^ swz)) = w;
        }
        __builtin_amdgcn_wave_barrier();

        // ---- A2: m=c, k natural (channels at own positions) ----
        bf16x8 a2[2];
#pragma unroll
        for (int kk = 0; kk < 2; ++kk) {
            const int byte = c * 128 + ((kk * 64 + g * 16) ^ ((c & 7) << 4));
            a2[kk] = *reinterpret_cast<const bf16x8*>(sl + byte);
        }
        __builtin_amdgcn_wave_barrier();   // WAR: before next tile's writes

        // ---- GEMM2 + bias ----
        f32x4 acc2[4];
#pragma unroll
        for (int t = 0; t < 4; ++t) {
            f32x4 ci = {b2v[t], b2v[t], b2v[t], b2v[t]};
            acc2[t] = __builtin_amdgcn_mfma_f32_16x16x32_bf16(a2[0], b2f[0][t], ci, 0, 0, 0);
            acc2[t] = __builtin_amdgcn_mfma_f32_16x16x32_bf16(a2[1], b2f[1][t], acc2[t], 0, 0, 0);
        }

        // ---- coalesced msg stores: lane (g,c) -> edge e0+g*4+r, bytes [8c,8c+8) ----
#pragma unroll
        for (int r = 0; r < 4; ++r) {
            const long long e = e0 + g * 4 + r;
            if (e < E) {
                uint2 v;
                v.x = pk_bf(acc2[0][r], acc2[1][r]);
                v.y = pk_bf(acc2[2][r], acc2[3][r]);
                *reinterpret_cast<uint2*>(msg + e * 32 + 2 * c) = v;
            }
        }
    }
}

// ======================= phase 2: gather + segment-sum + node MLP ==========
// Wave per node: walk CSR span, gather 128-B msg rows (2 rows per dword
// instruction), channel-sum in fp32, then node MLP, write out.
__global__ __launch_bounds__(256) void gather_node_kernel(
    const float* __restrict__ x,
    const unsigned* __restrict__ msg,
    const int* __restrict__ offsets,
    const int* __restrict__ eid,
    const float* __restrict__ W3,
    const float* __restrict__ b3,
    const float* __restrict__ W4,
    const float* __restrict__ b4,
    float* __restrict__ out,
    int nn)
{
    __shared__ __align__(16) float lds_s[4][EMBED];
    const int lane = threadIdx.x & 63;
    const int wave = threadIdx.x >> 6;
    const int dw = lane & 31;    // dword (2 channels) within the 128-B row
    const int rp = lane >> 5;    // row parity

    float w3c[EMBED], w4c[EMBED];
#pragma unroll
    for (int j = 0; j < EMBED; ++j) w3c[j] = W3[j * EMBED + lane];
#pragma unroll
    for (int j = 0; j < EMBED; ++j) w4c[j] = W4[j * EMBED + lane];
    const float b3v = b3[lane];
    const float b4v = b4[lane];

    const float4* s4 = reinterpret_cast<const float4*>(lds_s[wave]);
    const int wid = blockIdx.x * 4 + wave;
    const int nw  = gridDim.x * 4;

    for (int n = wid; n < nn; n += nw) {
        const int beg = offsets[n];
        const int end = offsets[n + 1];

        float s0 = 0.0f, s1 = 0.0f;
#pragma unroll 4
        for (int j = beg + rp; j < end; j += 2) {
            const int e = eid[j];                       // 2 addrs/wave, L2-hot
            const unsigned d = msg[(long long)e * 32 + dw];
            s0 += bf2f(d & 0xffffu);
            s1 += bf2f(d >> 16);
        }
        s0 += __shfl_xor(s0, 32, 64);
        s1 += __shfl_xor(s1, 32, 64);

        lds_s[wave][2 * dw]     = s0;   // lanes 32..63 duplicate same values
        lds_s[wave][2 * dw + 1] = s1;
        __builtin_amdgcn_wave_barrier();

        // ---- node MLP ----
        float acc = b3v;
#pragma unroll
        for (int j4 = 0; j4 < EMBED / 4; ++j4) {
            const float4 sv = s4[j4];
            acc = fmaf(sv.x, w3c[4 * j4 + 0], acc);
            acc = fmaf(sv.y, w3c[4 * j4 + 1], acc);
            acc = fmaf(sv.z, w3c[4 * j4 + 2], acc);
            acc = fmaf(sv.w, w3c[4 * j4 + 3], acc);
        }
        const float s = acc * __builtin_amdgcn_rcpf(1.0f + __expf(-acc));
        __builtin_amdgcn_wave_barrier();
        lds_s[wave][lane] = s;
        __builtin_amdgcn_wave_barrier();
        float acc2 = b4v;
#pragma unroll
        for (int j4 = 0; j4 < EMBED / 4; ++j4) {
            const float4 sv = s4[j4];
            acc2 = fmaf(sv.x, w4c[4 * j4 + 0], acc2);
            acc2 = fmaf(sv.y, w4c[4 * j4 + 1], acc2);
            acc2 = fmaf(sv.z, w4c[4 * j4 + 2], acc2);
            acc2 = fmaf(sv.w, w4c[4 * j4 + 3], acc2);
        }
        __builtin_amdgcn_wave_barrier();

        const long long base = (long long)n * EMBED + lane;
        out[base] = x[base] + acc2;
    }
}

// ======================= fallback: pk-f16 atomic path (round 5) ============
__device__ __forceinline__ unsigned pk_f16(float lo, float hi) {
    __half2 h = __halves2half2(__float2half_rn(lo), __float2half_rn(hi));
    return *reinterpret_cast<unsigned*>(&h);
}
__device__ __forceinline__ void atom_pk_add_f16(__half* addr, unsigned data) {
    asm volatile("global_atomic_pk_add_f16 %0, %1, off"
                 :: "v"(addr), "v"(data) : "memory");
}
__device__ __forceinline__ int ch_map(int t, int c) {  // (t&1)+2c+32(t>>1)
    return (t & 1) + 2 * c + 32 * (t >> 1);
}

template <bool USE_F16>
__global__ __launch_bounds__(256, 2) void edge_kernel_atomic(
    const float* __restrict__ coord, const float* __restrict__ rbf,
    const int* __restrict__ edge_index, const float* __restrict__ W1,
    const float* __restrict__ b1, const float* __restrict__ W2,
    const float* __restrict__ b2, void* __restrict__ aggv, long long E)
{
    __shared__ __align__(16) short lds_s[4][16 * 64];
    const int tid = threadIdx.x, lane = tid & 63, wave = tid >> 6;
    const int g = lane >> 4, c = lane & 15;
    const long long blk_e0 = (long long)blockIdx.x * 256;

    int ch[4];
#pragma unroll
    for (int t = 0; t < 4; ++t) ch[t] = ch_map(t, c);
    bf16x8 b1f[4];
#pragma unroll
    for (int t = 0; t < 4; ++t)
#pragma unroll
        for (int j = 0; j < 8; ++j) {
            const int k = g * 8 + j;
            b1f[t][j] = (k <= RBF) ? f2bf(W1[k * EMBED + ch[t]]) : (short)0;
        }
    bf16x8 b2f[2][4];
#pragma unroll
    for (int kk = 0; kk < 2; ++kk)
#pragma unroll
        for (int t = 0; t < 4; ++t)
#pragma unroll
            for (int j = 0; j < 8; ++j)
                b2f[kk][t][j] = f2bf(W2[(kk * 32 + g * 8 + j) * EMBED + ch[t]]);
    float b1v[4], b2v[4];
#pragma unroll
    for (int t = 0; t < 4; ++t) { b1v[t] = b1[ch[t]]; b2v[t] = b2[ch[t]]; }

    char* const sl = reinterpret_cast<char*>(lds_s[wave]);
    const long long wave_e0 = blk_e0 + (long long)wave * 64;
#pragma unroll 1
    for (int mt = 0; mt < 4; ++mt) {
        const long long e0 = wave_e0 + mt * 16;
        if (e0 >= E) break;
        bf16x8 a = {};
        const long long ea = e0 + c;
        const bool ev = (ea < E);
        if (g < 2) {
            if (ev) {
                const float4 p0 = *reinterpret_cast<const float4*>(rbf + ea * RBF + g * 8);
                const float4 p1 = *reinterpret_cast<const float4*>(rbf + ea * RBF + g * 8 + 4);
                a[0] = f2bf(p0.x); a[1] = f2bf(p0.y); a[2] = f2bf(p0.z); a[3] = f2bf(p0.w);
                a[4] = f2bf(p1.x); a[5] = f2bf(p1.y); a[6] = f2bf(p1.z); a[7] = f2bf(p1.w);
            }
        } else if (g == 2 && ev) {
            const int row = edge_index[ea];
            const int col = edge_index[E + ea];
            const float vx = coord[row * 3 + 0] - coord[col * 3 + 0];
            const float vy = coord[row * 3 + 1] - coord[col * 3 + 1];
            const float vz = coord[row * 3 + 2] - coord[col * 3 + 2];
            const float nrm = fmaxf(sqrtf(vx * vx + vy * vy + vz * vz), 1e-12f);
            const float inv = 1.0f / nrm;
            const float ux = vx * inv, uy = vy * inv, uz = vz * inv;
            const float cosang = fminf(fmaxf(-(ux * ux + uy * uy + uz * uz), -1.0f), 1.0f);
            a[0] = f2bf(acosf(cosang));
        }
        f32x4 acc1[4];
#pragma unroll
        for (int t = 0; t < 4; ++t) {
            f32x4 ci = {b1v[t], b1v[t], b1v[t], b1v[t]};
            acc1[t] = __builtin_amdgcn_mfma_f32_16x16x32_bf16(a, b1f[t], ci, 0, 0, 0);
        }
#pragma unroll
        for (int r = 0; r < 4; ++r) {
            const int erow = g * 4 + r;
            const int swz = (erow & 7) << 4;
            *reinterpret_cast<unsigned*>(sl + erow * 128 + ((4 * c) ^ swz)) =
                pk_bf(silu(acc1[0][r]), silu(acc1[1][r]));
            *reinterpret_cast<unsigned*>(sl + erow * 128 + ((64 + 4 * c) ^ swz)) =
                pk_bf(silu(acc1[2][r]), silu(acc1[3][r]));
        }
        __builtin_amdgcn_wave_barrier();
        bf16x8 a2[2];
#pragma unroll
        for (int kk = 0; kk < 2; ++kk)
            a2[kk] = *reinterpret_cast<const bf16x8*>(sl + c * 128 + ((kk * 64 + g * 16) ^ ((c & 7) << 4)));
        __builtin_amdgcn_wave_barrier();
        f32x4 acc2[4];
#pragma unroll
        for (int t = 0; t < 4; ++t) {
            f32x4 ci = {b2v[t], b2v[t], b2v[t], b2v[t]};
            acc2[t] = __builtin_amdgcn_mfma_f32_16x16x32_bf16(a2[0], b2f[0][t], ci, 0, 0, 0);
            acc2[t] = __builtin_amdgcn_mfma_f32_16x16x32_bf16(a2[1], b2f[1][t], acc2[t], 0, 0, 0);
        }
#pragma unroll
        for (int r = 0; r < 4; ++r) {
            const long long eat = e0 + g * 4 + r;
            if (eat < E) {
                const long long rowoff = (long long)edge_index[eat] * EMBED;
                if (USE_F16) {
                    __half* const dst = reinterpret_cast<__half*>(aggv) + rowoff;
                    atom_pk_add_f16(dst + 2 * c,      pk_f16(acc2[0][r], acc2[1][r]));
                    atom_pk_add_f16(dst + 32 + 2 * c, pk_f16(acc2[2][r], acc2[3][r]));
                } else {
                    float* const dst = reinterpret_cast<float*>(aggv) + rowoff;
                    atomicAdd(dst + ch[0], acc2[0][r]);
                    atomicAdd(dst + ch[1], acc2[1][r]);
                    atomicAdd(dst + ch[2], acc2[2][r]);
                    atomicAdd(dst + ch[3], acc2[3][r]);
                }
            }
        }
    }
}

template <bool USE_F16>
__global__ __launch_bounds__(256) void node_kernel(
    const float* __restrict__ x, const void* __restrict__ aggv,
    const float* __restrict__ W3, const float* __restrict__ b3,
    const float* __restrict__ W4, const float* __restrict__ b4,
    float* __restrict__ out, int nn)
{
    __shared__ __align__(16) float lds_s[4][EMBED];
    const int lane = threadIdx.x & 63;
    const int wave = threadIdx.x >> 6;
    float w3c[EMBED], w4c[EMBED];
#pragma unroll
    for (int j = 0; j < EMBED; ++j) w3c[j] = W3[j * EMBED + lane];
#pragma unroll
    for (int j = 0; j < EMBED; ++j) w4c[j] = W4[j * EMBED + lane];
    const float b3v = b3[lane];
    const float b4v = b4[lane];
    const float4* s4 = reinterpret_cast<const float4*>(lds_s[wave]);
    const int wid = blockIdx.x * 4 + wave;
    const int nw  = gridDim.x * 4;
    for (int n = wid; n < nn; n += nw) {
        const long long base = (long long)n * EMBED + lane;
        float a;
        if (USE_F16) a = __half2float(reinterpret_cast<const __half*>(aggv)[base]);
        else         a = reinterpret_cast<const float*>(aggv)[base];
        lds_s[wave][lane] = a;
        __builtin_amdgcn_wave_barrier();
        float acc = b3v;
#pragma unroll
        for (int j4 = 0; j4 < EMBED / 4; ++j4) {
            const float4 sv = s4[j4];
            acc = fmaf(sv.x, w3c[4 * j4 + 0], acc);
            acc = fmaf(sv.y, w3c[4 * j4 + 1], acc);
            acc = fmaf(sv.z, w3c[4 * j4 + 2], acc);
            acc = fmaf(sv.w, w3c[4 * j4 + 3], acc);
        }
        const float s = acc * __builtin_amdgcn_rcpf(1.0f + __expf(-acc));
        __builtin_amdgcn_wave_barrier();
        lds_s[wave][lane] = s;
        __builtin_amdgcn_wave_barrier();
        float acc2 = b4v;
#pragma unroll
        for (int j4 = 0; j4 < EMBED / 4; ++j4) {
            const float4 sv = s4[j4];
            acc2 = fmaf(sv.x, w4c[4 * j4 + 0], acc2);
            acc2 = fmaf(sv.y, w4c[4 * j4 + 1], acc2);
            acc2 = fmaf(sv.z, w4c[4 * j4 + 2], acc2);
            acc2 = fmaf(sv.w, w4c[4 * j4 + 3], acc2);
        }
        __builtin_amdgcn_wave_barrier();
        out[base] = x[base] + acc2;
    }
}

// ===========================================================================
extern "C" void kernel_launch(void* const* d_in, const int* in_sizes, int n_in,
                              void* d_out, int out_size, void* d_ws, size_t ws_size,
                              hipStream_t stream) {
    const float* x      = (const float*)d_in[0];
    const float* coord  = (const float*)d_in[1];
    const float* rbf    = (const float*)d_in[2];
    const int*   ei     = (const int*)d_in[3];
    const float* W1 = (const float*)d_in[4];
    const float* b1 = (const float*)d_in[5];
    const float* W2 = (const float*)d_in[6];
    const float* b2 = (const float*)d_in[7];
    const float* W3 = (const float*)d_in[8];
    const float* b3 = (const float*)d_in[9];
    const float* W4 = (const float*)d_in[10];
    const float* b4 = (const float*)d_in[11];
    float* out = (float*)d_out;

    const long long E = in_sizes[3] / 2;
    const int nn = in_sizes[0] / EMBED;
    const int nscan = (nn + SCAN_TILE - 1) / SCAN_TILE;
    const int nsPad = (nscan + 63) & ~63;

    // ws layout (full path): msg | eid | counts | offsets | bsums
    const size_t msgBytes = (size_t)E * 128;
    unsigned* msg  = (unsigned*)d_ws;
    int* eid       = (int*)((char*)d_ws + msgBytes);
    int* counts    = eid + E;
    int* offsets   = counts + nn;
    int* bsums     = offsets + nn + 1;
    const size_t neededFull = msgBytes + sizeof(int) * ((size_t)E + nn + (nn + 1) + nsPad);

    const unsigned egrid = (unsigned)((E + 255) / 256);

    if (ws_size >= neededFull) {
        // ---- CSR build ----
        hipMemsetAsync(counts, 0, sizeof(int) * nn, stream);
        k_hist<<<dim3(egrid), dim3(256), 0, stream>>>(ei, counts, E);
        k_scan1<<<dim3((unsigned)nscan), dim3(256), 0, stream>>>(counts, offsets, bsums, nn);
        k_scan2<<<dim3(1), dim3(64), 0, stream>>>(bsums, nscan);
        k_scan3<<<dim3((unsigned)nscan), dim3(256), 0, stream>>>(offsets, bsums, counts, nn, (int)E);
        k_scatter<<<dim3(egrid), dim3(256), 0, stream>>>(ei, offsets, counts, eid, E);
        // ---- phase 1: edge MLP -> msg (coalesced, no atomics) ----
        edge_msg_kernel<<<dim3(egrid), dim3(256), 0, stream>>>(
            coord, rbf, ei, W1, b1, W2, b2, msg, E);
        // ---- phase 2: gather + sum + node MLP ----
        gather_node_kernel<<<dim3(2048), dim3(256), 0, stream>>>(
            x, msg, offsets, eid, W3, b3, W4, b4, out, nn);
    } else if (ws_size >= (size_t)nn * EMBED * sizeof(__half)) {
        // ---- fallback: pk-f16 atomics (round-5 path, ~477 us) ----
        hipMemsetAsync(d_ws, 0, (size_t)nn * EMBED * sizeof(__half), stream);
        edge_kernel_atomic<true><<<dim3(egrid), dim3(256), 0, stream>>>(
            coord, rbf, ei, W1, b1, W2, b2, d_ws, E);
        node_kernel<true><<<dim3(2048), dim3(256), 0, stream>>>(
            x, d_ws, W3, b3, W4, b4, out, nn);
    } else {
        // ---- last resort: fp32 atomics into d_out ----
        hipMemsetAsync(out, 0, (size_t)nn * EMBED * sizeof(float), stream);
        edge_kernel_atomic<false><<<dim3(egrid), dim3(256), 0, stream>>>(
            coord, rbf, ei, W1, b1, W2, b2, out, E);
        node_kernel<false><<<dim3(2048), dim3(256), 0, stream>>>(
            x, out, W3, b3, W4, b4, out, nn);
    }
}

// Round 9
// 577.392 us; speedup vs baseline: 2.6641x; 1.7593x over previous
//
#include <hip/hip_runtime.h>
#include <hip/hip_fp16.h>
#include <hip/hip_bf16.h>

typedef __attribute__((ext_vector_type(8))) short bf16x8;
typedef __attribute__((ext_vector_type(4))) float f32x4;

constexpr int EMBED = 64;
constexpr int RBF   = 16;

__device__ __forceinline__ short f2bf(float f) {
    __hip_bfloat16 h = __float2bfloat16(f);   // RNE
    return *reinterpret_cast<short*>(&h);
}
__device__ __forceinline__ unsigned pk_bf(float lo, float hi) {
    unsigned l = (unsigned short)f2bf(lo);
    unsigned h = (unsigned short)f2bf(hi);
    return l | (h << 16);
}
__device__ __forceinline__ unsigned pk_f16(float lo, float hi) {
    __half2 h = __halves2half2(__float2half_rn(lo), __float2half_rn(hi));
    return *reinterpret_cast<unsigned*>(&h);
}
__device__ __forceinline__ void atom_pk_add_f16(__half* addr, unsigned data) {
    asm volatile("global_atomic_pk_add_f16 %0, %1, off"
                 :: "v"(addr), "v"(data) : "memory");
}
__device__ __forceinline__ float silu(float x) {
    return x * __builtin_amdgcn_rcpf(1.0f + __expf(-x));
}
// channel map (validated r5/r6): lane c, acc t -> channel (t&1)+2c+32(t>>1)
__device__ __forceinline__ int ch_map(int t, int c) {
    return (t & 1) + 2 * c + 32 * (t >> 1);
}

// ======================= W2 fragment table setup (once per launch) =========
// w2tbl[f][l], f = kk*4+t: lane l's B-fragment for GEMM2 K-step kk, acc t.
// Values identical to the register fragments of the round-5 passing kernel.
__global__ __launch_bounds__(64) void k_wsetup(
    const float* __restrict__ W2, bf16x8* __restrict__ w2tbl)
{
    const int l = threadIdx.x;
    const int g = l >> 4, c = l & 15;
#pragma unroll
    for (int kk = 0; kk < 2; ++kk)
#pragma unroll
        for (int t = 0; t < 4; ++t) {
            bf16x8 f;
            const int ch = ch_map(t, c);
#pragma unroll
            for (int j = 0; j < 8; ++j)
                f[j] = f2bf(W2[(kk * 32 + g * 8 + j) * EMBED + ch]);
            w2tbl[(kk * 4 + t) * 64 + l] = f;
        }
}

// ======================= edge kernel (W2 streamed from LDS) ================
template <bool GUARD, bool F16>
__global__ __launch_bounds__(256, 8) void edge_kernel(
    const float* __restrict__ coord,
    const float* __restrict__ rbf,
    const int* __restrict__ ei,
    const float* __restrict__ W1,
    const float* __restrict__ b1,
    const float* __restrict__ b2,
    const bf16x8* __restrict__ w2tbl_g,
    void* __restrict__ agg,
    int e_base, int E)
{
    __shared__ __align__(16) short lds_s[4][16 * 64];   // 8 KB msg tiles
    __shared__ __align__(16) bf16x8 w2s[8][64];         // 8 KB W2 fragments
    __shared__ int lds_row[256];

    const int tid  = threadIdx.x;
    const int lane = tid & 63;
    const int wave = tid >> 6;
    const int g = lane >> 4;
    const int c = lane & 15;
    const int blk_e0 = e_base + blockIdx.x * 256;

    // stage W2 table (coalesced 16B) + row indices
    {
        bf16x8* d = &w2s[0][0];
#pragma unroll
        for (int i = 0; i < 2; ++i) d[tid + 256 * i] = w2tbl_g[tid + 256 * i];
        const int e = blk_e0 + tid;
        lds_row[tid] = (!GUARD || e < E) ? ei[e] : 0;
    }
    __syncthreads();

    // ---- GEMM1 B-fragments in regs, ch_map columns (r6-validated) ----
    bf16x8 b1f[4];
    float b1v[4], b2v[4];
#pragma unroll
    for (int t = 0; t < 4; ++t) {
        const int ch = ch_map(t, c);
#pragma unroll
        for (int j = 0; j < 8; ++j) {
            const int k = g * 8 + j;
            b1f[t][j] = (k <= RBF) ? f2bf(W1[k * EMBED + ch]) : (short)0;
        }
        b1v[t] = b1[ch];
        b2v[t] = b2[ch];
    }

    char* const sl = reinterpret_cast<char*>(lds_s[wave]);
    const int e0w = blk_e0 + wave * 64;

#pragma unroll 1
    for (int mt = 0; mt < 4; ++mt) {
        const int e0 = e0w + mt * 16;
        if (GUARD && e0 >= E) break;
        const int el0 = wave * 64 + mt * 16;

        // ---- A1: m=c (edge), k=g*8+j ----
        bf16x8 a = {};
        const int ea = e0 + c;
        const bool ev = !GUARD || (ea < E);
        if (g < 2) {
            if (ev) {
                const float4 p0 = *reinterpret_cast<const float4*>(rbf + (long long)ea * RBF + g * 8);
                const float4 p1 = *reinterpret_cast<const float4*>(rbf + (long long)ea * RBF + g * 8 + 4);
                a[0] = f2bf(p0.x); a[1] = f2bf(p0.y); a[2] = f2bf(p0.z); a[3] = f2bf(p0.w);
                a[4] = f2bf(p1.x); a[5] = f2bf(p1.y); a[6] = f2bf(p1.z); a[7] = f2bf(p1.w);
            }
        } else if (g == 2 && ev) {
            // angle, faithful to reference
            const int row = lds_row[el0 + c];
            const int col = ei[E + ea];
            const float vx = coord[row * 3 + 0] - coord[col * 3 + 0];
            const float vy = coord[row * 3 + 1] - coord[col * 3 + 1];
            const float vz = coord[row * 3 + 2] - coord[col * 3 + 2];
            const float nrm = fmaxf(sqrtf(vx * vx + vy * vy + vz * vz), 1e-12f);
            const float inv = 1.0f / nrm;
            const float ux = vx * inv, uy = vy * inv, uz = vz * inv;
            const float cosang = fminf(fmaxf(-(ux * ux + uy * uy + uz * uz), -1.0f), 1.0f);
            a[0] = f2bf(acosf(cosang));
        }

        // ---- GEMM1 + bias ----
        f32x4 acc1[4];
#pragma unroll
        for (int t = 0; t < 4; ++t) {
            f32x4 ci = {b1v[t], b1v[t], b1v[t], b1v[t]};
            acc1[t] = __builtin_amdgcn_mfma_f32_16x16x32_bf16(a, b1f[t], ci, 0, 0, 0);
        }

        // ---- SiLU + packed bf16 swizzled LDS write (r6-validated) ----
#pragma unroll
        for (int r = 0; r < 4; ++r) {
            const int erow = g * 4 + r;
            const int swz = (erow & 7) << 4;
            *reinterpret_cast<unsigned*>(sl + erow * 128 + ((4 * c) ^ swz)) =
                pk_bf(silu(acc1[0][r]), silu(acc1[1][r]));
            *reinterpret_cast<unsigned*>(sl + erow * 128 + ((64 + 4 * c) ^ swz)) =
                pk_bf(silu(acc1[2][r]), silu(acc1[3][r]));
        }
        __builtin_amdgcn_wave_barrier();

        // ---- A2: m=c, k natural ----
        bf16x8 a2[2];
#pragma unroll
        for (int kk = 0; kk < 2; ++kk) {
            const int byte = c * 128 + ((kk * 64 + g * 16) ^ ((c & 7) << 4));
            a2[kk] = *reinterpret_cast<const bf16x8*>(sl + byte);
        }
        __builtin_amdgcn_wave_barrier();   // WAR vs next tile's writes

        // ---- GEMM2, B streamed from LDS (lane-stride 16B: conflict-free) ----
        f32x4 acc2[4];
#pragma unroll
        for (int t = 0; t < 4; ++t) {
            const bf16x8 bw0 = w2s[t][lane];
            const bf16x8 bw1 = w2s[4 + t][lane];
            f32x4 ci = {b2v[t], b2v[t], b2v[t], b2v[t]};
            acc2[t] = __builtin_amdgcn_mfma_f32_16x16x32_bf16(a2[0], bw0, ci, 0, 0, 0);
            acc2[t] = __builtin_amdgcn_mfma_f32_16x16x32_bf16(a2[1], bw1, acc2[t], 0, 0, 0);
        }

        // ---- scatter (r5-validated): lane holds edge g*4+r, chans ch_map ----
#pragma unroll
        for (int r = 0; r < 4; ++r) {
            const int eat = e0 + g * 4 + r;
            if (!GUARD || eat < E) {
                const unsigned row = (unsigned)lds_row[el0 + g * 4 + r];
                if (F16) {
                    __half* const dst = reinterpret_cast<__half*>(agg) + row * 64u;
                    atom_pk_add_f16(dst + 2 * c,      pk_f16(acc2[0][r], acc2[1][r]));
                    atom_pk_add_f16(dst + 32 + 2 * c, pk_f16(acc2[2][r], acc2[3][r]));
                } else {
                    float* const dst = reinterpret_cast<float*>(agg) + row * 64u;
                    atomicAdd(dst + 2 * c,      acc2[0][r]);
                    atomicAdd(dst + 2 * c + 1,  acc2[1][r]);
                    atomicAdd(dst + 32 + 2 * c, acc2[2][r]);
                    atomicAdd(dst + 33 + 2 * c, acc2[3][r]);
                }
            }
        }
    }
}

// ======================= node kernel (r5-validated) ========================
template <bool F16>
__global__ __launch_bounds__(256) void node_kernel(
    const float* __restrict__ x, const void* __restrict__ aggv,
    const float* __restrict__ W3, const float* __restrict__ b3,
    const float* __restrict__ W4, const float* __restrict__ b4,
    float* __restrict__ out, int nn)
{
    __shared__ __align__(16) float lds_s[4][EMBED];
    const int lane = threadIdx.x & 63;
    const int wave = threadIdx.x >> 6;
    float w3c[EMBED], w4c[EMBED];
#pragma unroll
    for (int j = 0; j < EMBED; ++j) w3c[j] = W3[j * EMBED + lane];
#pragma unroll
    for (int j = 0; j < EMBED; ++j) w4c[j] = W4[j * EMBED + lane];
    const float b3v = b3[lane];
    const float b4v = b4[lane];
    const float4* s4 = reinterpret_cast<const float4*>(lds_s[wave]);
    const int wid = blockIdx.x * 4 + wave;
    const int nw  = gridDim.x * 4;
    for (int n = wid; n < nn; n += nw) {
        const long long base = (long long)n * EMBED + lane;
        float a;
        if (F16) a = __half2float(reinterpret_cast<const __half*>(aggv)[base]);
        else     a = reinterpret_cast<const float*>(aggv)[base];
        lds_s[wave][lane] = a;
        __builtin_amdgcn_wave_barrier();
        float acc = b3v;
#pragma unroll
        for (int j4 = 0; j4 < EMBED / 4; ++j4) {
            const float4 sv = s4[j4];
            acc = fmaf(sv.x, w3c[4 * j4 + 0], acc);
            acc = fmaf(sv.y, w3c[4 * j4 + 1], acc);
            acc = fmaf(sv.z, w3c[4 * j4 + 2], acc);
            acc = fmaf(sv.w, w3c[4 * j4 + 3], acc);
        }
        const float s = acc * __builtin_amdgcn_rcpf(1.0f + __expf(-acc));
        __builtin_amdgcn_wave_barrier();
        lds_s[wave][lane] = s;
        __builtin_amdgcn_wave_barrier();
        float acc2 = b4v;
#pragma unroll
        for (int j4 = 0; j4 < EMBED / 4; ++j4) {
            const float4 sv = s4[j4];
            acc2 = fmaf(sv.x, w4c[4 * j4 + 0], acc2);
            acc2 = fmaf(sv.y, w4c[4 * j4 + 1], acc2);
            acc2 = fmaf(sv.z, w4c[4 * j4 + 2], acc2);
            acc2 = fmaf(sv.w, w4c[4 * j4 + 3], acc2);
        }
        __builtin_amdgcn_wave_barrier();
        out[base] = x[base] + acc2;
    }
}

// ===========================================================================
extern "C" void kernel_launch(void* const* d_in, const int* in_sizes, int n_in,
                              void* d_out, int out_size, void* d_ws, size_t ws_size,
                              hipStream_t stream) {
    const float* x      = (const float*)d_in[0];
    const float* coord  = (const float*)d_in[1];
    const float* rbf    = (const float*)d_in[2];
    const int*   ei     = (const int*)d_in[3];
    const float* W1 = (const float*)d_in[4];
    const float* b1 = (const float*)d_in[5];
    const float* W2 = (const float*)d_in[6];
    const float* b2 = (const float*)d_in[7];
    const float* W3 = (const float*)d_in[8];
    const float* b3 = (const float*)d_in[9];
    const float* W4 = (const float*)d_in[10];
    const float* b4 = (const float*)d_in[11];
    float* out = (float*)d_out;

    const int E  = (int)(in_sizes[3] / 2);
    const int nn = in_sizes[0] / EMBED;

    bf16x8* w2tbl = (bf16x8*)d_ws;                 // 8 KB table
    void* agg16 = (char*)d_ws + 16384;
    const size_t neededF16 = 16384 + (size_t)nn * EMBED * sizeof(__half);

    const int nfull = E / 256;
    const int rem   = E - nfull * 256;

    k_wsetup<<<dim3(1), dim3(64), 0, stream>>>(W2, w2tbl);

    if (ws_size >= neededF16) {
        hipMemsetAsync(agg16, 0, (size_t)nn * EMBED * sizeof(__half), stream);
        if (nfull)
            edge_kernel<false, true><<<dim3(nfull), dim3(256), 0, stream>>>(
                coord, rbf, ei, W1, b1, b2, w2tbl, agg16, 0, E);
        if (rem)
            edge_kernel<true, true><<<dim3(1), dim3(256), 0, stream>>>(
                coord, rbf, ei, W1, b1, b2, w2tbl, agg16, nfull * 256, E);
        node_kernel<true><<<dim3(2048), dim3(256), 0, stream>>>(
            x, agg16, W3, b3, W4, b4, out, nn);
    } else {
        // fallback: fp32 atomics into d_out, node MLP in place
        hipMemsetAsync(out, 0, (size_t)nn * EMBED * sizeof(float), stream);
        if (nfull)
            edge_kernel<false, false><<<dim3(nfull), dim3(256), 0, stream>>>(
                coord, rbf, ei, W1, b1, b2, w2tbl, out, 0, E);
        if (rem)
            edge_kernel<true, false><<<dim3(1), dim3(256), 0, stream>>>(
                coord, rbf, ei, W1, b1, b2, w2tbl, out, nfull * 256, E);
        node_kernel<false><<<dim3(2048), dim3(256), 0, stream>>>(
            x, out, W3, b3, W4, b4, out, nn);
    }
}

// Round 10
// 428.196 us; speedup vs baseline: 3.5924x; 1.3484x over previous
//
#include <hip/hip_runtime.h>
#include <hip/hip_fp16.h>
#include <hip/hip_bf16.h>

typedef __attribute__((ext_vector_type(8))) short bf16x8;
typedef __attribute__((ext_vector_type(4))) float f32x4;

constexpr int EMBED = 64;
constexpr int RBF   = 16;

__device__ __forceinline__ short f2bf(float f) {
    __hip_bfloat16 h = __float2bfloat16(f);   // RNE
    return *reinterpret_cast<short*>(&h);
}
__device__ __forceinline__ unsigned pk_bf(float lo, float hi) {
    unsigned l = (unsigned short)f2bf(lo);
    unsigned h = (unsigned short)f2bf(hi);
    return l | (h << 16);
}
__device__ __forceinline__ unsigned pk_f16(float lo, float hi) {
    __half2 h = __halves2half2(__float2half_rn(lo), __float2half_rn(hi));
    return *reinterpret_cast<unsigned*>(&h);
}
__device__ __forceinline__ void atom_pk_add_f16(__half* addr, unsigned data) {
    asm volatile("global_atomic_pk_add_f16 %0, %1, off"
                 :: "v"(addr), "v"(data) : "memory");
}
__device__ __forceinline__ float silu(float x) {
    return x * __builtin_amdgcn_rcpf(1.0f + __expf(-x));
}
// channel map (validated r5/r6/r9): lane c, acc t -> channel (t&1)+2c+32(t>>1)
__device__ __forceinline__ int ch_map(int t, int c) {
    return (t & 1) + 2 * c + 32 * (t >> 1);
}

// bf16 constants: bf16(pi) and bf16(pi/2) — exactly what f2bf(acosf(...))
// produces for non-degenerate / self-loop edges respectively (see analysis).
constexpr short BF16_PI  = (short)0x4049;   // 3.140625
constexpr short BF16_PI2 = (short)0x3FC9;   // 1.5703125

// ======================= edge kernel ==================================
// r5 structure (W1/W2 fragments VGPR-resident, pk-f16 atomic scatter),
// r9's lds_row staging + guard-split launch, angle replaced by constant.
template <bool GUARD, bool F16>
__global__ __launch_bounds__(256, 2) void edge_kernel(
    const float* __restrict__ rbf,
    const int* __restrict__ ei,
    const float* __restrict__ W1,
    const float* __restrict__ b1,
    const float* __restrict__ W2,
    const float* __restrict__ b2,
    void* __restrict__ agg,
    int e_base, int E)
{
    __shared__ __align__(16) short lds_s[4][16 * 64];   // 8 KB msg tiles
    __shared__ int lds_row[256];

    const int tid  = threadIdx.x;
    const int lane = tid & 63;
    const int wave = tid >> 6;
    const int g = lane >> 4;
    const int c = lane & 15;
    const int blk_e0 = e_base + blockIdx.x * 256;

    {
        const int e = blk_e0 + tid;
        lds_row[tid] = (!GUARD || e < E) ? ei[e] : 0;
    }
    __syncthreads();

    // ---- B fragments in regs, ch_map columns (r5/r6-validated) ----
    bf16x8 b1f[4];
    float b1v[4], b2v[4];
#pragma unroll
    for (int t = 0; t < 4; ++t) {
        const int ch = ch_map(t, c);
#pragma unroll
        for (int j = 0; j < 8; ++j) {
            const int k = g * 8 + j;
            b1f[t][j] = (k <= RBF) ? f2bf(W1[k * EMBED + ch]) : (short)0;
        }
        b1v[t] = b1[ch];
        b2v[t] = b2[ch];
    }
    bf16x8 b2f[2][4];
#pragma unroll
    for (int kk = 0; kk < 2; ++kk)
#pragma unroll
        for (int t = 0; t < 4; ++t) {
            const int ch = ch_map(t, c);
#pragma unroll
            for (int j = 0; j < 8; ++j)
                b2f[kk][t][j] = f2bf(W2[(kk * 32 + g * 8 + j) * EMBED + ch]);
        }

    char* const sl = reinterpret_cast<char*>(lds_s[wave]);
    const int e0w = blk_e0 + wave * 64;

#pragma unroll 1
    for (int mt = 0; mt < 4; ++mt) {
        const int e0 = e0w + mt * 16;
        if (GUARD && e0 >= E) break;
        const int el0 = wave * 64 + mt * 16;

        // ---- A1: m=c (edge), k=g*8+j ----
        bf16x8 a = {};
        const int ea = e0 + c;
        const bool ev = !GUARD || (ea < E);
        if (g < 2) {
            if (ev) {
                const float4 p0 = *reinterpret_cast<const float4*>(rbf + (long long)ea * RBF + g * 8);
                const float4 p1 = *reinterpret_cast<const float4*>(rbf + (long long)ea * RBF + g * 8 + 4);
                a[0] = f2bf(p0.x); a[1] = f2bf(p0.y); a[2] = f2bf(p0.z); a[3] = f2bf(p0.w);
                a[4] = f2bf(p1.x); a[5] = f2bf(p1.y); a[6] = f2bf(p1.z); a[7] = f2bf(p1.w);
            }
        } else if (g == 2 && ev) {
            // angle == bf16(pi), or bf16(pi/2) for self-loops (v == 0).
            // Bitwise-identical to f2bf(acosf(clip(-|v_hat|^2))) — see analysis.
            const int row = lds_row[el0 + c];
            const int col = ei[E + ea];
            a[0] = (row == col) ? BF16_PI2 : BF16_PI;
        }

        // ---- GEMM1 + bias ----
        f32x4 acc1[4];
#pragma unroll
        for (int t = 0; t < 4; ++t) {
            f32x4 ci = {b1v[t], b1v[t], b1v[t], b1v[t]};
            acc1[t] = __builtin_amdgcn_mfma_f32_16x16x32_bf16(a, b1f[t], ci, 0, 0, 0);
        }

        // ---- SiLU + packed bf16 swizzled LDS write (r6-validated) ----
#pragma unroll
        for (int r = 0; r < 4; ++r) {
            const int erow = g * 4 + r;
            const int swz = (erow & 7) << 4;
            *reinterpret_cast<unsigned*>(sl + erow * 128 + ((4 * c) ^ swz)) =
                pk_bf(silu(acc1[0][r]), silu(acc1[1][r]));
            *reinterpret_cast<unsigned*>(sl + erow * 128 + ((64 + 4 * c) ^ swz)) =
                pk_bf(silu(acc1[2][r]), silu(acc1[3][r]));
        }
        __builtin_amdgcn_wave_barrier();

        // ---- A2: m=c, k natural ----
        bf16x8 a2[2];
#pragma unroll
        for (int kk = 0; kk < 2; ++kk) {
            const int byte = c * 128 + ((kk * 64 + g * 16) ^ ((c & 7) << 4));
            a2[kk] = *reinterpret_cast<const bf16x8*>(sl + byte);
        }
        __builtin_amdgcn_wave_barrier();   // WAR vs next tile's writes

        // ---- GEMM2 + bias ----
        f32x4 acc2[4];
#pragma unroll
        for (int t = 0; t < 4; ++t) {
            f32x4 ci = {b2v[t], b2v[t], b2v[t], b2v[t]};
            acc2[t] = __builtin_amdgcn_mfma_f32_16x16x32_bf16(a2[0], b2f[0][t], ci, 0, 0, 0);
            acc2[t] = __builtin_amdgcn_mfma_f32_16x16x32_bf16(a2[1], b2f[1][t], acc2[t], 0, 0, 0);
        }

        // ---- scatter (r5-validated): lane holds edge g*4+r, chans ch_map ----
#pragma unroll
        for (int r = 0; r < 4; ++r) {
            const int eat = e0 + g * 4 + r;
            if (!GUARD || eat < E) {
                const unsigned row = (unsigned)lds_row[el0 + g * 4 + r];
                if (F16) {
                    __half* const dst = reinterpret_cast<__half*>(agg) + row * 64u;
                    atom_pk_add_f16(dst + 2 * c,      pk_f16(acc2[0][r], acc2[1][r]));
                    atom_pk_add_f16(dst + 32 + 2 * c, pk_f16(acc2[2][r], acc2[3][r]));
                } else {
                    float* const dst = reinterpret_cast<float*>(agg) + row * 64u;
                    atomicAdd(dst + 2 * c,      acc2[0][r]);
                    atomicAdd(dst + 2 * c + 1,  acc2[1][r]);
                    atomicAdd(dst + 32 + 2 * c, acc2[2][r]);
                    atomicAdd(dst + 33 + 2 * c, acc2[3][r]);
                }
            }
        }
    }
}

// ======================= node kernel (r5/r9-validated) =====================
template <bool F16>
__global__ __launch_bounds__(256) void node_kernel(
    const float* __restrict__ x, const void* __restrict__ aggv,
    const float* __restrict__ W3, const float* __restrict__ b3,
    const float* __restrict__ W4, const float* __restrict__ b4,
    float* __restrict__ out, int nn)
{
    __shared__ __align__(16) float lds_s[4][EMBED];
    const int lane = threadIdx.x & 63;
    const int wave = threadIdx.x >> 6;
    float w3c[EMBED], w4c[EMBED];
#pragma unroll
    for (int j = 0; j < EMBED; ++j) w3c[j] = W3[j * EMBED + lane];
#pragma unroll
    for (int j = 0; j < EMBED; ++j) w4c[j] = W4[j * EMBED + lane];
    const float b3v = b3[lane];
    const float b4v = b4[lane];
    const float4* s4 = reinterpret_cast<const float4*>(lds_s[wave]);
    const int wid = blockIdx.x * 4 + wave;
    const int nw  = gridDim.x * 4;
    for (int n = wid; n < nn; n += nw) {
        const long long base = (long long)n * EMBED + lane;
        float a;
        if (F16) a = __half2float(reinterpret_cast<const __half*>(aggv)[base]);
        else     a = reinterpret_cast<const float*>(aggv)[base];
        lds_s[wave][lane] = a;
        __builtin_amdgcn_wave_barrier();
        float acc = b3v;
#pragma unroll
        for (int j4 = 0; j4 < EMBED / 4; ++j4) {
            const float4 sv = s4[j4];
            acc = fmaf(sv.x, w3c[4 * j4 + 0], acc);
            acc = fmaf(sv.y, w3c[4 * j4 + 1], acc);
            acc = fmaf(sv.z, w3c[4 * j4 + 2], acc);
            acc = fmaf(sv.w, w3c[4 * j4 + 3], acc);
        }
        const float s = acc * __builtin_amdgcn_rcpf(1.0f + __expf(-acc));
        __builtin_amdgcn_wave_barrier();
        lds_s[wave][lane] = s;
        __builtin_amdgcn_wave_barrier();
        float acc2 = b4v;
#pragma unroll
        for (int j4 = 0; j4 < EMBED / 4; ++j4) {
            const float4 sv = s4[j4];
            acc2 = fmaf(sv.x, w4c[4 * j4 + 0], acc2);
            acc2 = fmaf(sv.y, w4c[4 * j4 + 1], acc2);
            acc2 = fmaf(sv.z, w4c[4 * j4 + 2], acc2);
            acc2 = fmaf(sv.w, w4c[4 * j4 + 3], acc2);
        }
        __builtin_amdgcn_wave_barrier();
        out[base] = x[base] + acc2;
    }
}

// ===========================================================================
extern "C" void kernel_launch(void* const* d_in, const int* in_sizes, int n_in,
                              void* d_out, int out_size, void* d_ws, size_t ws_size,
                              hipStream_t stream) {
    const float* x      = (const float*)d_in[0];
    const float* rbf    = (const float*)d_in[2];
    const int*   ei     = (const int*)d_in[3];
    const float* W1 = (const float*)d_in[4];
    const float* b1 = (const float*)d_in[5];
    const float* W2 = (const float*)d_in[6];
    const float* b2 = (const float*)d_in[7];
    const float* W3 = (const float*)d_in[8];
    const float* b3 = (const float*)d_in[9];
    const float* W4 = (const float*)d_in[10];
    const float* b4 = (const float*)d_in[11];
    float* out = (float*)d_out;

    const int E  = (int)(in_sizes[3] / 2);
    const int nn = in_sizes[0] / EMBED;

    void* agg16 = d_ws;
    const size_t neededF16 = (size_t)nn * EMBED * sizeof(__half);

    const int nfull = E / 256;
    const int rem   = E - nfull * 256;

    if (ws_size >= neededF16) {
        hipMemsetAsync(agg16, 0, neededF16, stream);
        if (nfull)
            edge_kernel<false, true><<<dim3(nfull), dim3(256), 0, stream>>>(
                rbf, ei, W1, b1, W2, b2, agg16, 0, E);
        if (rem)
            edge_kernel<true, true><<<dim3(1), dim3(256), 0, stream>>>(
                rbf, ei, W1, b1, W2, b2, agg16, nfull * 256, E);
        node_kernel<true><<<dim3(2048), dim3(256), 0, stream>>>(
            x, agg16, W3, b3, W4, b4, out, nn);
    } else {
        // fallback: fp32 atomics into d_out, node MLP in place
        hipMemsetAsync(out, 0, (size_t)nn * EMBED * sizeof(float), stream);
        if (nfull)
            edge_kernel<false, false><<<dim3(nfull), dim3(256), 0, stream>>>(
                rbf, ei, W1, b1, W2, b2, out, 0, E);
        if (rem)
            edge_kernel<true, false><<<dim3(1), dim3(256), 0, stream>>>(
                rbf, ei, W1, b1, W2, b2, out, nfull * 256, E);
        node_kernel<false><<<dim3(2048), dim3(256), 0, stream>>>(
            x, out, W3, b3, W4, b4, out, nn);
    }
}